// Round 2
// baseline (474.736 us; speedup 1.0000x reference)
//
#include <hip/hip_runtime.h>
#include <stdint.h>

// ---------------------------------------------------------------------------
// MixingLayer: b=16, m=64, f=128, k=64, L2=16, LMAX=4. ALL I/O IS FP32.
// SEG = [0,1,1,1,2,2,2,2,2,3,3,3,3,3,3,3]
//
// Pipeline (ws layout):
//   K0 conv_kernel:  Wb[n][kk] bf16, n=0:64 wx0 | 64:128 wy0       ws+0        (16.8MB)
//   K1 g_kernel:     G[bm][kk] bf16, kk = fy*512 + fx*4 + l        ws+16.8MB   (134MB)
//   K2 gemm_kernel:  Cpart[32][bm][n] fp32 split-K partials        ws+151MB    (16.8MB)
//   K3 finish_kernel: reduce + MLP + silu gates + output
// ---------------------------------------------------------------------------

#define AS1 __attribute__((address_space(1)))
#define AS3 __attribute__((address_space(3)))

typedef __bf16 bf16x8 __attribute__((ext_vector_type(8)));
typedef float f32x4 __attribute__((ext_vector_type(4)));

__device__ __forceinline__ uint16_t f2b(float f) {
  uint32_t u = __float_as_uint(f);
  u += 0x7fffu + ((u >> 16) & 1u);   // RNE
  return (uint16_t)(u >> 16);
}

__device__ __forceinline__ void load16(const float* __restrict__ p, float* o) {
#pragma unroll
  for (int i = 0; i < 4; ++i) {
    float4 v = *(const float4*)(p + i * 4);
    o[i * 4 + 0] = v.x; o[i * 4 + 1] = v.y; o[i * 4 + 2] = v.z; o[i * 4 + 3] = v.w;
  }
}

// ---------------------------------------------------------------------------
// K0: Wb[n*65536+kk] = bf16( n<64 ? wx0 : wy0 )
// ---------------------------------------------------------------------------
__global__ __launch_bounds__(256) void conv_kernel(const float* __restrict__ wx0,
                                                   const float* __restrict__ wy0,
                                                   uint16_t* __restrict__ Wb) {
  size_t i = ((size_t)blockIdx.x * 256 + threadIdx.x) * 8;
  const size_t half = (size_t)64 * 65536;
  const float* src = (i < half) ? (wx0 + i) : (wy0 + (i - half));
  float4 v0 = *(const float4*)src;
  float4 v1 = *(const float4*)(src + 4);
  uint32_t o0 = (uint32_t)f2b(v0.x) | ((uint32_t)f2b(v0.y) << 16);
  uint32_t o1 = (uint32_t)f2b(v0.z) | ((uint32_t)f2b(v0.w) << 16);
  uint32_t o2 = (uint32_t)f2b(v1.x) | ((uint32_t)f2b(v1.y) << 16);
  uint32_t o3 = (uint32_t)f2b(v1.z) | ((uint32_t)f2b(v1.w) << 16);
  *(uint4*)(Wb + i) = make_uint4(o0, o1, o2, o3);
}

// ---------------------------------------------------------------------------
// K1: G[bm][fy*512 + fx*4 + l] = sum_{c in seg l} y[bm,fy,c] * x[bm,fx,c]
// ---------------------------------------------------------------------------
__global__ __launch_bounds__(256) void g_kernel(const float* __restrict__ x,
                                                const float* __restrict__ y,
                                                uint16_t* __restrict__ G) {
  const int seg[16] = {0,1,1,1,2,2,2,2,2,3,3,3,3,3,3,3};
  int bm = blockIdx.x;
  int w = threadIdx.x >> 6, lane = threadIdx.x & 63;
  const float* xb = x + (size_t)bm * 2048;
  const float* yb = y + (size_t)bm * 2048;
  uint16_t* gout = G + (size_t)bm * 65536;

  float xv[2][16];
  load16(xb + lane * 32, xv[0]);       // fx = 2*lane
  load16(xb + lane * 32 + 16, xv[1]);  // fx = 2*lane+1

  for (int it = 0; it < 32; ++it) {
    int fy = it * 4 + w;
    float yv[16];
    load16(yb + fy * 16, yv);
    float acc[2][4] = {{0.f,0.f,0.f,0.f},{0.f,0.f,0.f,0.f}};
#pragma unroll
    for (int c = 0; c < 16; ++c) {
      acc[0][seg[c]] += yv[c] * xv[0][c];
      acc[1][seg[c]] += yv[c] * xv[1][c];
    }
    uint32_t o0 = (uint32_t)f2b(acc[0][0]) | ((uint32_t)f2b(acc[0][1]) << 16);
    uint32_t o1 = (uint32_t)f2b(acc[0][2]) | ((uint32_t)f2b(acc[0][3]) << 16);
    uint32_t o2 = (uint32_t)f2b(acc[1][0]) | ((uint32_t)f2b(acc[1][1]) << 16);
    uint32_t o3 = (uint32_t)f2b(acc[1][2]) | ((uint32_t)f2b(acc[1][3]) << 16);
    *(uint4*)(gout + fy * 512 + lane * 8) = make_uint4(o0, o1, o2, o3);
  }
}

// ---------------------------------------------------------------------------
// K2: split-K GEMM. Cpart[split][m][n] = sum_{kk in split} G[m][kk] * Wb[n][kk]
// ---------------------------------------------------------------------------
__device__ __forceinline__ void gload_lds16(const void* g, void* l) {
  __builtin_amdgcn_global_load_lds((const AS1 uint32_t*)g, (AS3 uint32_t*)l, 16, 0, 0);
}

__global__ __launch_bounds__(256) void gemm_kernel(const uint16_t* __restrict__ G,
                                                   const uint16_t* __restrict__ Wb,
                                                   float* __restrict__ Cpart) {
  __shared__ __align__(16) uint16_t sA[128 * 32];   // [m][k] bf16
  __shared__ __align__(16) uint16_t sB[128 * 32];   // [n][k] bf16

  int tid = threadIdx.x;
  int w = tid >> 6, lane = tid & 63;
  int m0 = blockIdx.x * 128;
  int kkbase = blockIdx.y * 2048;      // 2048 kk per split = 64 steps of 32
  int r = lane & 15, q = lane >> 4;
  int wm = w >> 1, wn = w & 1;
  int qq = lane & 3, rowl = lane >> 2;

  f32x4 zero = {0.f, 0.f, 0.f, 0.f};
  f32x4 acc[4][4];
#pragma unroll
  for (int i = 0; i < 4; ++i)
#pragma unroll
    for (int j = 0; j < 4; ++j) acc[i][j] = zero;

  for (int ks = 0; ks < 64; ++ks) {
    int kk0 = kkbase + ks * 32;
    __syncthreads();  // previous step's LDS reads done
#pragma unroll
    for (int jj = 0; jj < 2; ++jj) {
      int blk = w * 2 + jj;          // wave-uniform
      int row = blk * 16 + rowl;
      gload_lds16(G  + (size_t)(m0 + row) * 65536 + kk0 + qq * 8, &sA[blk * 512]);
      gload_lds16(Wb + (size_t)row        * 65536 + kk0 + qq * 8, &sB[blk * 512]);
    }
    __syncthreads();  // drains vmcnt(0) before LDS reads

    bf16x8 a[4], b[4];
#pragma unroll
    for (int i = 0; i < 4; ++i)
      a[i] = *(const bf16x8*)&sA[(wm * 64 + i * 16 + r) * 32 + q * 8];
#pragma unroll
    for (int j = 0; j < 4; ++j)
      b[j] = *(const bf16x8*)&sB[(wn * 64 + j * 16 + r) * 32 + q * 8];
#pragma unroll
    for (int i = 0; i < 4; ++i)
#pragma unroll
      for (int j = 0; j < 4; ++j)
        acc[i][j] = __builtin_amdgcn_mfma_f32_16x16x32_bf16(a[i], b[j], acc[i][j], 0, 0, 0);
  }

  // C/D layout: col(n)=lane&15, row(m)=(lane>>4)*4+reg
  float* cbase = Cpart + (size_t)blockIdx.y * 131072;  // 1024*128
#pragma unroll
  for (int i = 0; i < 4; ++i)
#pragma unroll
    for (int j = 0; j < 4; ++j)
#pragma unroll
      for (int reg = 0; reg < 4; ++reg) {
        int mm = m0 + wm * 64 + i * 16 + q * 4 + reg;
        int nn = wn * 64 + j * 16 + r;
        cbase[(size_t)mm * 128 + nn] = acc[i][j][reg];
      }
}

// ---------------------------------------------------------------------------
// K3: reduce 32 partials -> mx,my[64]; 2 MLP stages (bias depends on m=bm&63);
// gates = silu(m2 . wf[l,f,:]); out[f,c] = gx[f,seg[c]]*x + gy[f,seg[c]]*y.
// ---------------------------------------------------------------------------
__global__ __launch_bounds__(256) void finish_kernel(
    const float* __restrict__ x, const float* __restrict__ y,
    const float* __restrict__ wx_mlp, const float* __restrict__ bx_mlp,
    const float* __restrict__ wy_mlp, const float* __restrict__ by_mlp,
    const float* __restrict__ wxf, const float* __restrict__ wyf,
    const float* __restrict__ Cpart, float* __restrict__ out) {
  const int seg[16] = {0,1,1,1,2,2,2,2,2,3,3,3,3,3,3,3};
  __shared__ float sm[128];
  __shared__ float sg[2][128][4];
  int t = threadIdx.x;

  for (int bi = 0; bi < 8; ++bi) {
    int bm = blockIdx.x * 8 + bi;
    int mi = bm & 63;

    if (t < 128) {
      float s = 0.f;
      for (int sp = 0; sp < 32; ++sp)
        s += Cpart[(size_t)sp * 131072 + (size_t)bm * 128 + t];
      sm[t] = s;  // [0:64)=mx, [64:128)=my
    }
    __syncthreads();

    for (int st = 0; st < 2; ++st) {
      float v = 0.f;
      if (t < 128) {
        int side = t >> 6, j = t & 63;
        const float* wmlp = side ? wy_mlp : wx_mlp;
        const float* bmlp = side ? by_mlp : bx_mlp;
        const float* mv = sm + side * 64;
        for (int k = 0; k < 64; ++k)
          v += mv[k] * wmlp[(st * 64 + k) * 64 + j];
        v += bmlp[(st * 64 + mi) * 64 + j];
        v = v / (1.f + __expf(-v));  // silu
      }
      __syncthreads();
      if (t < 128) sm[t] = v;
      __syncthreads();
    }

    {  // gates
      int side = t >> 7, f = t & 127;
      const float* wf = side ? wyf : wxf;
      const float* mv = sm + side * 64;
#pragma unroll
      for (int l = 0; l < 4; ++l) {
        const float* wp = wf + ((size_t)l * 128 + f) * 64;
        float v = 0.f;
        for (int k = 0; k < 64; ++k) v += mv[k] * wp[k];
        sg[side][f][l] = v / (1.f + __expf(-v));
      }
    }
    __syncthreads();

    {  // output: thread -> (f, half of c-range), 8 floats
      int f = t >> 1, half = t & 1;
      size_t base = ((size_t)bm * 128 + f) * 16 + half * 8;
      float4 xa = *(const float4*)(x + base), xb4 = *(const float4*)(x + base + 4);
      float4 ya = *(const float4*)(y + base), yb4 = *(const float4*)(y + base + 4);
      float xv[8] = {xa.x, xa.y, xa.z, xa.w, xb4.x, xb4.y, xb4.z, xb4.w};
      float yv[8] = {ya.x, ya.y, ya.z, ya.w, yb4.x, yb4.y, yb4.z, yb4.w};
      float o[8];
#pragma unroll
      for (int ii = 0; ii < 8; ++ii) {
        int c = half * 8 + ii;
        o[ii] = sg[0][f][seg[c]] * xv[ii] + sg[1][f][seg[c]] * yv[ii];
      }
      *(float4*)(out + base)     = make_float4(o[0], o[1], o[2], o[3]);
      *(float4*)(out + base + 4) = make_float4(o[4], o[5], o[6], o[7]);
    }
    __syncthreads();
  }
}

// ---------------------------------------------------------------------------
extern "C" void kernel_launch(void* const* d_in, const int* in_sizes, int n_in,
                              void* d_out, int out_size, void* d_ws, size_t ws_size,
                              hipStream_t stream) {
  const float* x      = (const float*)d_in[0];
  const float* y      = (const float*)d_in[1];
  const float* wx0    = (const float*)d_in[2];
  const float* wy0    = (const float*)d_in[3];
  const float* wx_mlp = (const float*)d_in[4];
  const float* bx_mlp = (const float*)d_in[5];
  const float* wy_mlp = (const float*)d_in[6];
  const float* by_mlp = (const float*)d_in[7];
  const float* wxf    = (const float*)d_in[8];
  const float* wyf    = (const float*)d_in[9];
  float* out = (float*)d_out;

  uint16_t* Wb    = (uint16_t*)d_ws;                                // 16,777,216 B
  uint16_t* G     = (uint16_t*)((char*)d_ws + (size_t)16777216);    // 134,217,728 B
  float*    Cpart = (float*)((char*)d_ws + (size_t)150994944);      // 16,777,216 B

  conv_kernel<<<4096, 256, 0, stream>>>(wx0, wy0, Wb);
  g_kernel<<<1024, 256, 0, stream>>>(x, y, G);
  gemm_kernel<<<dim3(8, 32), 256, 0, stream>>>(G, Wb, Cpart);
  finish_kernel<<<128, 256, 0, stream>>>(x, y, wx_mlp, bx_mlp, wy_mlp, by_mlp,
                                         wxf, wyf, Cpart, out);
}

// Round 3
// 238.493 us; speedup vs baseline: 1.9906x; 1.9906x over previous
//
#include <hip/hip_runtime.h>
#include <stdint.h>

// ---------------------------------------------------------------------------
// MixingLayer: b=16, m=64, f=128, k=64, L2=16, LMAX=4. ALL I/O IS FP32.
// SEG = [0,1,1,1,2,2,2,2,2,3,3,3,3,3,3,3]
//
// Pipeline (ws layout):
//   K0 conv_kernel:  Wb[n][kk] bf16, n=0:64 wx0 | 64:128 wy0       ws+0        (16.8MB)
//   K1 g_kernel:     G[bm][kk] bf16, kk = fy*512 + fx*4 + l        ws+16.8MB   (134MB)
//   K2 gemm_kernel:  Cpart[32][bm][n] fp32 split-K partials        ws+151MB    (16.8MB)
//   K4 wft_kernel:   wfT[side][k][l][f] f32 (256KB) — OVERLAYS Wb region
//                    (safe: stream-ordered after gemm_kernel's last Wb read)
//   K3 finish_kernel: 1 block/bm: reduce + MLP + silu gates + output
// ---------------------------------------------------------------------------

#define AS1 __attribute__((address_space(1)))
#define AS3 __attribute__((address_space(3)))

typedef __bf16 bf16x8 __attribute__((ext_vector_type(8)));
typedef float f32x4 __attribute__((ext_vector_type(4)));

__device__ __forceinline__ uint16_t f2b(float f) {
  uint32_t u = __float_as_uint(f);
  u += 0x7fffu + ((u >> 16) & 1u);   // RNE
  return (uint16_t)(u >> 16);
}

__device__ __forceinline__ void load16(const float* __restrict__ p, float* o) {
#pragma unroll
  for (int i = 0; i < 4; ++i) {
    float4 v = *(const float4*)(p + i * 4);
    o[i * 4 + 0] = v.x; o[i * 4 + 1] = v.y; o[i * 4 + 2] = v.z; o[i * 4 + 3] = v.w;
  }
}

// ---------------------------------------------------------------------------
// K0: Wb[n*65536+kk] = bf16( n<64 ? wx0 : wy0 )
// ---------------------------------------------------------------------------
__global__ __launch_bounds__(256) void conv_kernel(const float* __restrict__ wx0,
                                                   const float* __restrict__ wy0,
                                                   uint16_t* __restrict__ Wb) {
  size_t i = ((size_t)blockIdx.x * 256 + threadIdx.x) * 8;
  const size_t half = (size_t)64 * 65536;
  const float* src = (i < half) ? (wx0 + i) : (wy0 + (i - half));
  float4 v0 = *(const float4*)src;
  float4 v1 = *(const float4*)(src + 4);
  uint32_t o0 = (uint32_t)f2b(v0.x) | ((uint32_t)f2b(v0.y) << 16);
  uint32_t o1 = (uint32_t)f2b(v0.z) | ((uint32_t)f2b(v0.w) << 16);
  uint32_t o2 = (uint32_t)f2b(v1.x) | ((uint32_t)f2b(v1.y) << 16);
  uint32_t o3 = (uint32_t)f2b(v1.z) | ((uint32_t)f2b(v1.w) << 16);
  *(uint4*)(Wb + i) = make_uint4(o0, o1, o2, o3);
}

// ---------------------------------------------------------------------------
// K1: G[bm][fy*512 + fx*4 + l] = sum_{c in seg l} y[bm,fy,c] * x[bm,fx,c]
// ---------------------------------------------------------------------------
__global__ __launch_bounds__(256) void g_kernel(const float* __restrict__ x,
                                                const float* __restrict__ y,
                                                uint16_t* __restrict__ G) {
  const int seg[16] = {0,1,1,1,2,2,2,2,2,3,3,3,3,3,3,3};
  int bm = blockIdx.x;
  int w = threadIdx.x >> 6, lane = threadIdx.x & 63;
  const float* xb = x + (size_t)bm * 2048;
  const float* yb = y + (size_t)bm * 2048;
  uint16_t* gout = G + (size_t)bm * 65536;

  float xv[2][16];
  load16(xb + lane * 32, xv[0]);       // fx = 2*lane
  load16(xb + lane * 32 + 16, xv[1]);  // fx = 2*lane+1

  for (int it = 0; it < 32; ++it) {
    int fy = it * 4 + w;
    float yv[16];
    load16(yb + fy * 16, yv);
    float acc[2][4] = {{0.f,0.f,0.f,0.f},{0.f,0.f,0.f,0.f}};
#pragma unroll
    for (int c = 0; c < 16; ++c) {
      acc[0][seg[c]] += yv[c] * xv[0][c];
      acc[1][seg[c]] += yv[c] * xv[1][c];
    }
    uint32_t o0 = (uint32_t)f2b(acc[0][0]) | ((uint32_t)f2b(acc[0][1]) << 16);
    uint32_t o1 = (uint32_t)f2b(acc[0][2]) | ((uint32_t)f2b(acc[0][3]) << 16);
    uint32_t o2 = (uint32_t)f2b(acc[1][0]) | ((uint32_t)f2b(acc[1][1]) << 16);
    uint32_t o3 = (uint32_t)f2b(acc[1][2]) | ((uint32_t)f2b(acc[1][3]) << 16);
    *(uint4*)(gout + fy * 512 + lane * 8) = make_uint4(o0, o1, o2, o3);
  }
}

// ---------------------------------------------------------------------------
// K2: split-K GEMM. Cpart[split][m][n] = sum_{kk in split} G[m][kk] * Wb[n][kk]
// ---------------------------------------------------------------------------
__device__ __forceinline__ void gload_lds16(const void* g, void* l) {
  __builtin_amdgcn_global_load_lds((const AS1 uint32_t*)g, (AS3 uint32_t*)l, 16, 0, 0);
}

__global__ __launch_bounds__(256) void gemm_kernel(const uint16_t* __restrict__ G,
                                                   const uint16_t* __restrict__ Wb,
                                                   float* __restrict__ Cpart) {
  __shared__ __align__(16) uint16_t sA[128 * 32];   // [m][k] bf16
  __shared__ __align__(16) uint16_t sB[128 * 32];   // [n][k] bf16

  int tid = threadIdx.x;
  int w = tid >> 6, lane = tid & 63;
  int m0 = blockIdx.x * 128;
  int kkbase = blockIdx.y * 2048;      // 2048 kk per split = 64 steps of 32
  int r = lane & 15, q = lane >> 4;
  int wm = w >> 1, wn = w & 1;
  int qq = lane & 3, rowl = lane >> 2;

  f32x4 zero = {0.f, 0.f, 0.f, 0.f};
  f32x4 acc[4][4];
#pragma unroll
  for (int i = 0; i < 4; ++i)
#pragma unroll
    for (int j = 0; j < 4; ++j) acc[i][j] = zero;

  for (int ks = 0; ks < 64; ++ks) {
    int kk0 = kkbase + ks * 32;
    __syncthreads();  // previous step's LDS reads done
#pragma unroll
    for (int jj = 0; jj < 2; ++jj) {
      int blk = w * 2 + jj;          // wave-uniform
      int row = blk * 16 + rowl;
      gload_lds16(G  + (size_t)(m0 + row) * 65536 + kk0 + qq * 8, &sA[blk * 512]);
      gload_lds16(Wb + (size_t)row        * 65536 + kk0 + qq * 8, &sB[blk * 512]);
    }
    __syncthreads();  // drains vmcnt(0) before LDS reads

    bf16x8 a[4], b[4];
#pragma unroll
    for (int i = 0; i < 4; ++i)
      a[i] = *(const bf16x8*)&sA[(wm * 64 + i * 16 + r) * 32 + q * 8];
#pragma unroll
    for (int j = 0; j < 4; ++j)
      b[j] = *(const bf16x8*)&sB[(wn * 64 + j * 16 + r) * 32 + q * 8];
#pragma unroll
    for (int i = 0; i < 4; ++i)
#pragma unroll
      for (int j = 0; j < 4; ++j)
        acc[i][j] = __builtin_amdgcn_mfma_f32_16x16x32_bf16(a[i], b[j], acc[i][j], 0, 0, 0);
  }

  // C/D layout: col(n)=lane&15, row(m)=(lane>>4)*4+reg
  float* cbase = Cpart + (size_t)blockIdx.y * 131072;  // 1024*128
#pragma unroll
  for (int i = 0; i < 4; ++i)
#pragma unroll
    for (int j = 0; j < 4; ++j)
#pragma unroll
      for (int reg = 0; reg < 4; ++reg) {
        int mm = m0 + wm * 64 + i * 16 + q * 4 + reg;
        int nn = wn * 64 + j * 16 + r;
        cbase[(size_t)mm * 128 + nn] = acc[i][j][reg];
      }
}

// ---------------------------------------------------------------------------
// K4: wfT[((side*64+k)*4+l)*128+f] = wf_side[(l*128+f)*64+k]
// 65536 elements; writes coalesced in f. Tiny (256 KB).
// ---------------------------------------------------------------------------
__global__ __launch_bounds__(256) void wft_kernel(const float* __restrict__ wxf,
                                                  const float* __restrict__ wyf,
                                                  float* __restrict__ wfT) {
  int idx = blockIdx.x * 256 + threadIdx.x;   // 65536 total
  int side = idx >> 15;
  int rem = idx & 32767;
  int k = rem >> 9;
  int l = (rem >> 7) & 3;
  int f = rem & 127;
  const float* src = side ? wyf : wxf;
  wfT[idx] = src[((size_t)l * 128 + f) * 64 + k];
}

// ---------------------------------------------------------------------------
// K3: ONE BLOCK PER bm (1024 blocks, 256 thr).
//   reduce 32 partials -> sm[128] (mx|my)
//   2 MLP stages (bias bmlp[st][m][j], m = bm&63!)  [threads 0..127]
//   gates via wfT (coalesced, side = wave-uniform)   [all 256 threads]
//   out[f,c] = gx[f,seg[c]]*x + gy[f,seg[c]]*y       [coalesced float4 x2]
// ---------------------------------------------------------------------------
__global__ __launch_bounds__(256) void finish_kernel(
    const float* __restrict__ x, const float* __restrict__ y,
    const float* __restrict__ wx_mlp, const float* __restrict__ bx_mlp,
    const float* __restrict__ wy_mlp, const float* __restrict__ by_mlp,
    const float* __restrict__ wfT,
    const float* __restrict__ Cpart, float* __restrict__ out) {
  const int seg[16] = {0,1,1,1,2,2,2,2,2,3,3,3,3,3,3,3};
  __shared__ float sm[128];
  __shared__ float sg[2][128][4];
  int t = threadIdx.x;
  int bm = blockIdx.x;
  int mi = bm & 63;

  // --- split-K reduce: mx = sm[0:64), my = sm[64:128)
  if (t < 128) {
    float s = 0.f;
#pragma unroll
    for (int sp = 0; sp < 32; ++sp)
      s += Cpart[(size_t)sp * 131072 + (size_t)bm * 128 + t];
    sm[t] = s;
  }
  __syncthreads();

  // --- 2 MLP stages (silu)
  for (int st = 0; st < 2; ++st) {
    float v = 0.f;
    if (t < 128) {
      int side = t >> 6, j = t & 63;
      const float* wmlp = side ? wy_mlp : wx_mlp;
      const float* bmlp = side ? by_mlp : bx_mlp;
      const float* mv = sm + side * 64;
#pragma unroll 8
      for (int k = 0; k < 64; ++k)
        v += mv[k] * wmlp[(st * 64 + k) * 64 + j];
      v += bmlp[(st * 64 + mi) * 64 + j];
      v = v / (1.f + __expf(-v));
    }
    __syncthreads();
    if (t < 128) sm[t] = v;
    __syncthreads();
  }

  // --- gates: side wave-uniform (t>>7), f = t&127; coalesced wfT reads
  {
    int side = t >> 7, f = t & 127;
    const float* base = wfT + side * 32768;  // [k][l][f]
    const float* mv = sm + side * 64;
    float g[4] = {0.f, 0.f, 0.f, 0.f};
#pragma unroll 8
    for (int k = 0; k < 64; ++k) {
      float m2 = mv[k];
#pragma unroll
      for (int l = 0; l < 4; ++l)
        g[l] += m2 * base[(k * 4 + l) * 128 + f];
    }
#pragma unroll
    for (int l = 0; l < 4; ++l)
      sg[side][f][l] = g[l] / (1.f + __expf(-g[l]));
  }
  __syncthreads();

  // --- output: thread -> (f, half), 8 floats each; fully coalesced
  {
    int f = t >> 1, half = t & 1;
    size_t base = ((size_t)bm * 128 + f) * 16 + half * 8;
    float4 xa = *(const float4*)(x + base), xb4 = *(const float4*)(x + base + 4);
    float4 ya = *(const float4*)(y + base), yb4 = *(const float4*)(y + base + 4);
    float xv[8] = {xa.x, xa.y, xa.z, xa.w, xb4.x, xb4.y, xb4.z, xb4.w};
    float yv[8] = {ya.x, ya.y, ya.z, ya.w, yb4.x, yb4.y, yb4.z, yb4.w};
    float o[8];
#pragma unroll
    for (int ii = 0; ii < 8; ++ii) {
      int c = half * 8 + ii;
      o[ii] = sg[0][f][seg[c]] * xv[ii] + sg[1][f][seg[c]] * yv[ii];
    }
    *(float4*)(out + base)     = make_float4(o[0], o[1], o[2], o[3]);
    *(float4*)(out + base + 4) = make_float4(o[4], o[5], o[6], o[7]);
  }
}

// ---------------------------------------------------------------------------
extern "C" void kernel_launch(void* const* d_in, const int* in_sizes, int n_in,
                              void* d_out, int out_size, void* d_ws, size_t ws_size,
                              hipStream_t stream) {
  const float* x      = (const float*)d_in[0];
  const float* y      = (const float*)d_in[1];
  const float* wx0    = (const float*)d_in[2];
  const float* wy0    = (const float*)d_in[3];
  const float* wx_mlp = (const float*)d_in[4];
  const float* bx_mlp = (const float*)d_in[5];
  const float* wy_mlp = (const float*)d_in[6];
  const float* by_mlp = (const float*)d_in[7];
  const float* wxf    = (const float*)d_in[8];
  const float* wyf    = (const float*)d_in[9];
  float* out = (float*)d_out;

  uint16_t* Wb    = (uint16_t*)d_ws;                                // 16,777,216 B
  uint16_t* G     = (uint16_t*)((char*)d_ws + (size_t)16777216);    // 134,217,728 B
  float*    Cpart = (float*)((char*)d_ws + (size_t)150994944);      // 16,777,216 B
  float*    wfT   = (float*)d_ws;  // overlays Wb — written AFTER gemm_kernel

  conv_kernel<<<4096, 256, 0, stream>>>(wx0, wy0, Wb);
  g_kernel<<<1024, 256, 0, stream>>>(x, y, G);
  gemm_kernel<<<dim3(8, 32), 256, 0, stream>>>(G, Wb, Cpart);
  wft_kernel<<<256, 256, 0, stream>>>(wxf, wyf, wfT);
  finish_kernel<<<1024, 256, 0, stream>>>(x, y, wx_mlp, bx_mlp, wy_mlp, by_mlp,
                                          wfT, Cpart, out);
}